// Round 7
// baseline (160.248 us; speedup 1.0000x reference)
//
#include <hip/hip_runtime.h>
#include <stdint.h>

// ---------------------------------------------------------------------------
// PlaneEmbeddingNetwork, round 13: pool-after-fco, zero cross-lane main loop.
// R12 (46us): LDS=0 achieved, MfmaUtil 21%, but dur flat vs R11 -- mixed
// regime: serial MFMA chain + ~975 VALU/wave + 27us memory floor at occ 56%.
// R13:
//  1. Mean-pool COMMUTES with fco (linear). h C-output == A-frag of H^T
//     (duality), so: relu in-reg, repack, fco = A(relu H^T) x B(Wfco)
//     (same ws words as before -- B-frag of M == A-frag of M^T; fold_w
//     byte-identical). fco C-out rows = 4 tokens of ONE face -> pool = 3
//     in-lane adds. Deletes the whole DPP pool block (~160 VALU/wave), the
//     4x output replication, and ALL cross-lane ops from the main loop.
//  2. __launch_bounds__(256,8): VGPR 36 << 64 cap; raise occupancy for
//     gather-latency hiding (R12 stuck at 56%).
// Predict: dur ~38-41us, VALUBusy ~46%, MfmaUtil ~25%, occ ~70%, VGPR<=64
// (no scratch), absmax ~0.0039 class.
// ---------------------------------------------------------------------------

typedef _Float16 v2h __attribute__((ext_vector_type(2)));
typedef __fp16 h4 __attribute__((ext_vector_type(4)));   // MFMA A/B frag
typedef float f32x4 __attribute__((ext_vector_type(4)));
typedef uint32_t u32x2 __attribute__((ext_vector_type(2)));

static __device__ __forceinline__ v2h pkh(float a, float b) {
    v2h r; r.x = (_Float16)a; r.y = (_Float16)b; return r;  // RNE (setup only)
}
static __device__ __forceinline__ v2h pkrtz(float a, float b) {
#if __has_builtin(__builtin_amdgcn_cvt_pkrtz)
    return __builtin_bit_cast(v2h, __builtin_amdgcn_cvt_pkrtz(a, b));
#else
    return pkh(a, b);
#endif
}
static __device__ __forceinline__ uint32_t bcu(v2h h) {
    return __builtin_bit_cast(uint32_t, h);
}
static __device__ __forceinline__ h4 mkh4(uint32_t lo, uint32_t hi) {
    u32x2 t; t.x = lo; t.y = hi; return __builtin_bit_cast(h4, t);
}
static __device__ __forceinline__ h4 ld2h(const uint32_t* p) {
    u32x2 t; t.x = p[0]; t.y = p[1]; return __builtin_bit_cast(h4, t);
}
static __device__ __forceinline__ f32x4 mfma16(h4 a, h4 b, f32x4 c) {
    return __builtin_amdgcn_mfma_f32_16x16x16f16(a, b, c, 0, 0, 0);
}
// pack a C fragment (4 f32 regs) into an A/B fragment (4 halves)
static __device__ __forceinline__ h4 packC(f32x4 c) {
    return mkh4(bcu(pkrtz(c[0], c[1])), bcu(pkrtz(c[2], c[3])));
}
// relu + pack C fragment
static __device__ __forceinline__ h4 packCrelu(f32x4 c) {
    return mkh4(bcu(pkrtz(fmaxf(c[0], 0.f), fmaxf(c[1], 0.f))),
                bcu(pkrtz(fmaxf(c[2], 0.f), fmaxf(c[3], 0.f))));
}
// zero-select a fragment (v_cndmask x2 on the packed dwords)
static __device__ __forceinline__ h4 selh(bool keep, h4 x) {
    u32x2 t = __builtin_bit_cast(u32x2, x);
    u32x2 r; r.x = keep ? t.x : 0u; r.y = keep ? t.y : 0u;
    return __builtin_bit_cast(h4, r);
}

// ---------------------------------------------------------------------------
// fold_w: byte-identical to R11/R12 (B-frag of M == A-frag of M^T).
// ws layout (dwords):
//  [0   .. 384): Eqkv[T][l][d]: B-frag of w_in block T (q,k,v)
//  [384 .. 640): Eh[b][l][d]:   B-frag of W1 col-tile b (== A-frag of W1^T)
//  [640 .. 672): b1[c] f32
//  [672 ..1184): Efco[kt*2+n][l][d]: B-frag of 0.25*fco_w rows 16kt.., cols 16n..
// ---------------------------------------------------------------------------
__global__ void fold_w(const float* __restrict__ w_in,
                       const float* __restrict__ w_out,
                       const float* __restrict__ b_out,
                       const float* __restrict__ fc_w,
                       const float* __restrict__ fc_b,
                       const float* __restrict__ fco_w,
                       uint32_t* __restrict__ wsu) {
    const int tid = threadIdx.x;
    if (blockIdx.x == 0) {
        if (tid < 384) {                   // Eqkv
            const int T = tid >> 7, r = tid & 127, l = r >> 1, d = r & 1;
            const int o = 16 * T + (l & 15), k0 = 4 * (l >> 4) + 2 * d;
            wsu[tid] = bcu(pkh(w_in[k0 * 48 + o], w_in[(k0 + 1) * 48 + o]));
        } else if (tid < 640) {            // Eh
            const int i = tid - 384, b = i >> 7, r = i & 127, l = r >> 1, d = r & 1;
            const int c = 16 * b + (l & 15), k0 = 4 * (l >> 4) + 2 * d;
            float a0 = 0.f, a1 = 0.f;
#pragma unroll
            for (int e = 0; e < 16; ++e) {
                a0 = fmaf(w_out[k0 * 16 + e],       fc_w[e * 32 + c], a0);
                a1 = fmaf(w_out[(k0 + 1) * 16 + e], fc_w[e * 32 + c], a1);
            }
            wsu[tid] = bcu(pkh(a0, a1));
        }
    } else {
        if (tid < 32) {                    // b1 (f32)
            float acc = fc_b[tid];
#pragma unroll
            for (int e = 0; e < 16; ++e)
                acc = fmaf(b_out[e], fc_w[e * 32 + tid], acc);
            reinterpret_cast<float*>(wsu)[640 + tid] = acc;
        } else if (tid < 544) {            // Efco (0.25 pooling folded in)
            const int i = tid - 32;
            const int kt = i >> 8, n = (i >> 7) & 1, r = i & 127, l = r >> 1, d = r & 1;
            const int col = 16 * n + (l & 15), k0 = 16 * kt + 4 * (l >> 4) + 2 * d;
            wsu[672 + i] = bcu(pkh(fco_w[k0 * 32 + col] * 0.25f,
                                   fco_w[(k0 + 1) * 32 + col] * 0.25f));
        }
    }
}

__launch_bounds__(256, 8)
__global__ void face_net(const float* __restrict__ node,
                         const int*   __restrict__ fids,
                         const float* __restrict__ b_in,
                         const uint32_t* __restrict__ wsu,
                         const float* __restrict__ fco_b,
                         float* __restrict__ out, int F) {
    const int l   = threadIdx.x & 63;
    const int wid = threadIdx.x >> 6;
    const int token_base = blockIdx.x * 256 + wid * 64;   // wave = 64 tokens
    const int total = 4 * F;
    if (token_base >= total) return;
    const int c0 = l & 15, g2 = l >> 4;

    // ---- gathers up front: lane holds token 16a+c0, comps 4g2..4g2+3.
    h4 X[4];
#pragma unroll
    for (int a = 0; a < 4; ++a) {
        int tok = token_base + 16 * a + c0;
        tok = tok < total ? tok : total - 1;
        const int nid = fids[tok];
        const float4 xv = *reinterpret_cast<const float4*>(
            node + (size_t)nid * 16 + g2 * 4);
        X[a] = mkh4(bcu(pkrtz(xv.x, xv.y)), bcu(pkrtz(xv.z, xv.w)));
    }

    // ---- weight fragments (ws hot in cache)
    const h4 WqT  = ld2h(wsu + 0   + l * 2);   // A-frag of Wq^T
    const h4 WkT  = ld2h(wsu + 128 + l * 2);   // A-frag of Wk^T
    const h4 WvB  = ld2h(wsu + 256 + l * 2);   // B-frag of Wv
    const h4 EhA0 = ld2h(wsu + 384 + l * 2);   // A-frag of W1^T, hid 0..15
    const h4 EhA1 = ld2h(wsu + 512 + l * 2);   // A-frag of W1^T, hid 16..31
    const h4 Ef00 = ld2h(wsu + 672 + 0 * 128 + l * 2);  // B-frag 0.25Wfco k0,n0
    const h4 Ef01 = ld2h(wsu + 672 + 1 * 128 + l * 2);  // k0,n1
    const h4 Ef10 = ld2h(wsu + 672 + 2 * 128 + l * 2);  // k1,n0
    const h4 Ef11 = ld2h(wsu + 672 + 3 * 128 + l * 2);  // k1,n1

    // ---- biases
    const float4 bq4 = *reinterpret_cast<const float4*>(b_in + 4 * g2);
    const float  bv  = b_in[32 + c0];
    const float* b1f = reinterpret_cast<const float*>(wsu) + 640;
    const float4 b10 = *reinterpret_cast<const float4*>(b1f + 4 * g2);
    const float4 b11 = *reinterpret_cast<const float4*>(b1f + 16 + 4 * g2);
    const float fb0s = fco_b[c0];        // col-indexed now (fco C cols = oc)
    const float fb1s = fco_b[16 + c0];

    const bool scoreH0 = (g2 < 2);          // scores A: comps 0..7 = head0
    const bool pvH0    = (c0 < 8);          // PV A: v-comp rows 0..7 = head0
    const bool valid   = (g2 == (c0 >> 2)); // lane holds its face's S column
    const int fbase = token_base >> 2;
    const float C = 0.51006974841f;         // (1/sqrt(8)) * log2(e)
    const f32x4 zz = {0.f, 0.f, 0.f, 0.f};

#pragma unroll
    for (int a = 0; a < 4; ++a) {
        // ---- qkv (q,k transposed; v plain). k-bias dropped (const over keys).
        f32x4 cq = {bq4.x, bq4.y, bq4.z, bq4.w};
        f32x4 cv = {bv, bv, bv, bv};
        const f32x4 Dq = mfma16(WqT, X[a], cq);   // Q^T[qcomp][token]
        const f32x4 Dk = mfma16(WkT, X[a], zz);   // K^T[kcomp][token]
        const f32x4 Dv = mfma16(X[a], WvB, cv);   // V[token][vcomp]
        const h4 qB = packC(Dq);   // B-frag: Q^T (contract comps)
        const h4 kA = packC(Dk);   // A-frag: K[token][comp]
        const h4 vA = packC(Dv);   // A-frag: V^T[vcomp][token]

        // ---- scores: S^T = K.Q^T per head (head = masked comp-half of A)
        const f32x4 S0 = mfma16(selh(scoreH0,  kA), qB, zz);
        const f32x4 S1 = mfma16(selh(!scoreH0, kA), qB, zz);

        // ---- in-lane softmax over the 4 regs (valid lanes: g2==c0>>2)
        const float e00 = __builtin_amdgcn_exp2f(S0[0] * C);
        const float e01 = __builtin_amdgcn_exp2f(S0[1] * C);
        const float e02 = __builtin_amdgcn_exp2f(S0[2] * C);
        const float e03 = __builtin_amdgcn_exp2f(S0[3] * C);
        const float e10 = __builtin_amdgcn_exp2f(S1[0] * C);
        const float e11 = __builtin_amdgcn_exp2f(S1[1] * C);
        const float e12 = __builtin_amdgcn_exp2f(S1[2] * C);
        const float e13 = __builtin_amdgcn_exp2f(S1[3] * C);
        const float r0 = __builtin_amdgcn_rcpf((e00 + e01) + (e02 + e03));
        const float r1 = __builtin_amdgcn_rcpf((e10 + e11) + (e12 + e13));
        // P^T B-frags; block-diagonal structure via zeroing invalid lanes
        const h4 PB0 = selh(valid, mkh4(bcu(pkrtz(e00 * r0, e01 * r0)),
                                        bcu(pkrtz(e02 * r0, e03 * r0))));
        const h4 PB1 = selh(valid, mkh4(bcu(pkrtz(e10 * r1, e11 * r1)),
                                        bcu(pkrtz(e12 * r1, e13 * r1))));

        // ---- PV: O^T = V^T.P^T, heads via masked v-comp rows, C-chained
        f32x4 Ot = mfma16(selh(pvH0,  vA), PB0, zz);
        Ot       = mfma16(selh(!pvH0, vA), PB1, Ot);
        const h4 hB = packC(Ot);   // B-frag: O^T (contract comps)

        // ---- h: H = W1^T.O^T (+b1); C-out col=token, rows=hid comps
        f32x4 ch0 = {b10.x, b10.y, b10.z, b10.w};
        f32x4 ch1 = {b11.x, b11.y, b11.z, b11.w};
        const f32x4 H0 = mfma16(EhA0, hB, ch0);
        const f32x4 H1 = mfma16(EhA1, hB, ch1);

        // ---- relu+pack: H C-out == A-frag of relu(H)^T (K = hid tile)
        const h4 AH0 = packCrelu(H0);
        const h4 AH1 = packCrelu(H1);

        // ---- fco per token: out'[tok][oc] = relu(H)^T x 0.25*Wfco.
        //      C-out col=oc, rows = tokens 4g2..4g2+3 = ONE face ->
        //      pool = 3 in-lane adds (0.25 pre-folded), bias added once.
        const f32x4 O0 = mfma16(AH1, Ef10, mfma16(AH0, Ef00, zz));
        const f32x4 O1 = mfma16(AH1, Ef11, mfma16(AH0, Ef01, zz));
        const float o0 = ((O0[0] + O0[1]) + (O0[2] + O0[3])) + fb0s;
        const float o1 = ((O1[0] + O1[1]) + (O1[2] + O1[3])) + fb1s;

        // ---- store: lane (c0,g2) -> face fbase+4a+g2, cols c0 / 16+c0
        const int face = fbase + 4 * a + g2;
        if (face < F) {
            float* ob = out + (size_t)face * 32;
            ob[c0]      = o0;
            ob[16 + c0] = o1;
        }
    }
}

extern "C" void kernel_launch(void* const* d_in, const int* in_sizes, int n_in,
                              void* d_out, int out_size, void* d_ws, size_t ws_size,
                              hipStream_t stream) {
    const float* node  = (const float*)d_in[0];
    const int*   fids  = (const int*)  d_in[1];
    const float* w_in  = (const float*)d_in[2];
    const float* b_in  = (const float*)d_in[3];
    const float* w_out = (const float*)d_in[4];
    const float* b_out = (const float*)d_in[5];
    const float* fc_w  = (const float*)d_in[6];
    const float* fc_b  = (const float*)d_in[7];
    const float* fco_w = (const float*)d_in[8];
    const float* fco_b = (const float*)d_in[9];
    float* out = (float*)d_out;
    uint32_t* wsu = (uint32_t*)d_ws;
    const int F = in_sizes[1] / 4;

    hipLaunchKernelGGL(fold_w, dim3(2), dim3(640), 0, stream,
                       w_in, w_out, b_out, fc_w, fc_b, fco_w, wsu);
    const int threads = F * 4;
    const int blocks = (threads + 255) / 256;
    hipLaunchKernelGGL(face_net, dim3(blocks), dim3(256), 0, stream,
                       node, fids, b_in, wsu, fco_b, out, F);
}

// Round 8
// 132.834 us; speedup vs baseline: 1.2064x; 1.2064x over previous
//
#include <hip/hip_runtime.h>
#include <stdint.h>

// ---------------------------------------------------------------------------
// PlaneEmbeddingNetwork, round 14: R13 + coalesced full-line stores.
// R13 post-mortem: pool-after-fco algebra fine (occ 71%, VGPR 32, absmax
// bit-identical) but 2 scalar-dword stores/lane covered only 64B of each
// 128B output line per instruction -> RFO + write amplification
// (WRITE 62.5->140.6MB, FETCH +47MB) -> memory-bound at 74us.
// R14: quad transpose via 6 DPP rot + 4 selects; lane t=0 of each quad
// stores float4 = o0 of lanes 0..3 (cols 4q..), lane t=1 stores float4 =
// o1 of lanes 0..3 (cols 16+4q..). One store instruction = 4 consecutive
// faces x full 128B line = 512B contiguous. ~12 VALU/iter added.
// Predict: WRITE 62500KB, FETCH ~105MB, dur ~33-38us, VALUBusy ~68%,
// MfmaUtil ~19%, occ ~70%, absmax 0.0039 class.
// ---------------------------------------------------------------------------

typedef _Float16 v2h __attribute__((ext_vector_type(2)));
typedef __fp16 h4 __attribute__((ext_vector_type(4)));   // MFMA A/B frag
typedef float f32x4 __attribute__((ext_vector_type(4)));
typedef uint32_t u32x2 __attribute__((ext_vector_type(2)));

#define DPP_ROT1 0x39  // lane t <- (t+1)&3 within quad
#define DPP_ROT2 0x4E  // lane t <- (t+2)&3
#define DPP_ROT3 0x93  // lane t <- (t+3)&3

template<int CTRL>
static __device__ __forceinline__ float dppf(float x) {
    return __builtin_bit_cast(float,
        __builtin_amdgcn_mov_dpp(__builtin_bit_cast(int, x), CTRL, 0xF, 0xF, true));
}

static __device__ __forceinline__ v2h pkh(float a, float b) {
    v2h r; r.x = (_Float16)a; r.y = (_Float16)b; return r;  // RNE (setup only)
}
static __device__ __forceinline__ v2h pkrtz(float a, float b) {
#if __has_builtin(__builtin_amdgcn_cvt_pkrtz)
    return __builtin_bit_cast(v2h, __builtin_amdgcn_cvt_pkrtz(a, b));
#else
    return pkh(a, b);
#endif
}
static __device__ __forceinline__ uint32_t bcu(v2h h) {
    return __builtin_bit_cast(uint32_t, h);
}
static __device__ __forceinline__ h4 mkh4(uint32_t lo, uint32_t hi) {
    u32x2 t; t.x = lo; t.y = hi; return __builtin_bit_cast(h4, t);
}
static __device__ __forceinline__ h4 ld2h(const uint32_t* p) {
    u32x2 t; t.x = p[0]; t.y = p[1]; return __builtin_bit_cast(h4, t);
}
static __device__ __forceinline__ f32x4 mfma16(h4 a, h4 b, f32x4 c) {
    return __builtin_amdgcn_mfma_f32_16x16x16f16(a, b, c, 0, 0, 0);
}
// pack a C fragment (4 f32 regs) into an A/B fragment (4 halves)
static __device__ __forceinline__ h4 packC(f32x4 c) {
    return mkh4(bcu(pkrtz(c[0], c[1])), bcu(pkrtz(c[2], c[3])));
}
// relu + pack C fragment
static __device__ __forceinline__ h4 packCrelu(f32x4 c) {
    return mkh4(bcu(pkrtz(fmaxf(c[0], 0.f), fmaxf(c[1], 0.f))),
                bcu(pkrtz(fmaxf(c[2], 0.f), fmaxf(c[3], 0.f))));
}
// zero-select a fragment (v_cndmask x2 on the packed dwords)
static __device__ __forceinline__ h4 selh(bool keep, h4 x) {
    u32x2 t = __builtin_bit_cast(u32x2, x);
    u32x2 r; r.x = keep ? t.x : 0u; r.y = keep ? t.y : 0u;
    return __builtin_bit_cast(h4, r);
}

// ---------------------------------------------------------------------------
// fold_w: byte-identical to R11/R12/R13 (B-frag of M == A-frag of M^T).
// ws layout (dwords):
//  [0   .. 384): Eqkv[T][l][d]: B-frag of w_in block T (q,k,v)
//  [384 .. 640): Eh[b][l][d]:   B-frag of W1 col-tile b (== A-frag of W1^T)
//  [640 .. 672): b1[c] f32
//  [672 ..1184): Efco[kt*2+n][l][d]: B-frag of 0.25*fco_w rows 16kt.., cols 16n..
// ---------------------------------------------------------------------------
__global__ void fold_w(const float* __restrict__ w_in,
                       const float* __restrict__ w_out,
                       const float* __restrict__ b_out,
                       const float* __restrict__ fc_w,
                       const float* __restrict__ fc_b,
                       const float* __restrict__ fco_w,
                       uint32_t* __restrict__ wsu) {
    const int tid = threadIdx.x;
    if (blockIdx.x == 0) {
        if (tid < 384) {                   // Eqkv
            const int T = tid >> 7, r = tid & 127, l = r >> 1, d = r & 1;
            const int o = 16 * T + (l & 15), k0 = 4 * (l >> 4) + 2 * d;
            wsu[tid] = bcu(pkh(w_in[k0 * 48 + o], w_in[(k0 + 1) * 48 + o]));
        } else if (tid < 640) {            // Eh
            const int i = tid - 384, b = i >> 7, r = i & 127, l = r >> 1, d = r & 1;
            const int c = 16 * b + (l & 15), k0 = 4 * (l >> 4) + 2 * d;
            float a0 = 0.f, a1 = 0.f;
#pragma unroll
            for (int e = 0; e < 16; ++e) {
                a0 = fmaf(w_out[k0 * 16 + e],       fc_w[e * 32 + c], a0);
                a1 = fmaf(w_out[(k0 + 1) * 16 + e], fc_w[e * 32 + c], a1);
            }
            wsu[tid] = bcu(pkh(a0, a1));
        }
    } else {
        if (tid < 32) {                    // b1 (f32)
            float acc = fc_b[tid];
#pragma unroll
            for (int e = 0; e < 16; ++e)
                acc = fmaf(b_out[e], fc_w[e * 32 + tid], acc);
            reinterpret_cast<float*>(wsu)[640 + tid] = acc;
        } else if (tid < 544) {            // Efco (0.25 pooling folded in)
            const int i = tid - 32;
            const int kt = i >> 8, n = (i >> 7) & 1, r = i & 127, l = r >> 1, d = r & 1;
            const int col = 16 * n + (l & 15), k0 = 16 * kt + 4 * (l >> 4) + 2 * d;
            wsu[672 + i] = bcu(pkh(fco_w[k0 * 32 + col] * 0.25f,
                                   fco_w[(k0 + 1) * 32 + col] * 0.25f));
        }
    }
}

__launch_bounds__(256, 8)
__global__ void face_net(const float* __restrict__ node,
                         const int*   __restrict__ fids,
                         const float* __restrict__ b_in,
                         const uint32_t* __restrict__ wsu,
                         const float* __restrict__ fco_b,
                         float* __restrict__ out, int F) {
    const int l   = threadIdx.x & 63;
    const int wid = threadIdx.x >> 6;
    const int token_base = blockIdx.x * 256 + wid * 64;   // wave = 64 tokens
    const int total = 4 * F;
    if (token_base >= total) return;
    const int c0 = l & 15, g2 = l >> 4;

    // ---- gathers up front: lane holds token 16a+c0, comps 4g2..4g2+3.
    h4 X[4];
#pragma unroll
    for (int a = 0; a < 4; ++a) {
        int tok = token_base + 16 * a + c0;
        tok = tok < total ? tok : total - 1;
        const int nid = fids[tok];
        const float4 xv = *reinterpret_cast<const float4*>(
            node + (size_t)nid * 16 + g2 * 4);
        X[a] = mkh4(bcu(pkrtz(xv.x, xv.y)), bcu(pkrtz(xv.z, xv.w)));
    }

    // ---- weight fragments (ws hot in cache)
    const h4 WqT  = ld2h(wsu + 0   + l * 2);   // A-frag of Wq^T
    const h4 WkT  = ld2h(wsu + 128 + l * 2);   // A-frag of Wk^T
    const h4 WvB  = ld2h(wsu + 256 + l * 2);   // B-frag of Wv
    const h4 EhA0 = ld2h(wsu + 384 + l * 2);   // A-frag of W1^T, hid 0..15
    const h4 EhA1 = ld2h(wsu + 512 + l * 2);   // A-frag of W1^T, hid 16..31
    const h4 Ef00 = ld2h(wsu + 672 + 0 * 128 + l * 2);  // B-frag 0.25Wfco k0,n0
    const h4 Ef01 = ld2h(wsu + 672 + 1 * 128 + l * 2);  // k0,n1
    const h4 Ef10 = ld2h(wsu + 672 + 2 * 128 + l * 2);  // k1,n0
    const h4 Ef11 = ld2h(wsu + 672 + 3 * 128 + l * 2);  // k1,n1

    // ---- biases
    const float4 bq4 = *reinterpret_cast<const float4*>(b_in + 4 * g2);
    const float  bv  = b_in[32 + c0];
    const float* b1f = reinterpret_cast<const float*>(wsu) + 640;
    const float4 b10 = *reinterpret_cast<const float4*>(b1f + 4 * g2);
    const float4 b11 = *reinterpret_cast<const float4*>(b1f + 16 + 4 * g2);
    const float fb0s = fco_b[c0];        // col-indexed (fco C cols = oc)
    const float fb1s = fco_b[16 + c0];

    const bool scoreH0 = (g2 < 2);          // scores A: comps 0..7 = head0
    const bool pvH0    = (c0 < 8);          // PV A: v-comp rows 0..7 = head0
    const bool valid   = (g2 == (c0 >> 2)); // lane holds its face's S column
    const int fbase = token_base >> 2;
    const float C = 0.51006974841f;         // (1/sqrt(8)) * log2(e)
    const f32x4 zz = {0.f, 0.f, 0.f, 0.f};

#pragma unroll
    for (int a = 0; a < 4; ++a) {
        // ---- qkv (q,k transposed; v plain). k-bias dropped (const over keys).
        f32x4 cq = {bq4.x, bq4.y, bq4.z, bq4.w};
        f32x4 cv = {bv, bv, bv, bv};
        const f32x4 Dq = mfma16(WqT, X[a], cq);   // Q^T[qcomp][token]
        const f32x4 Dk = mfma16(WkT, X[a], zz);   // K^T[kcomp][token]
        const f32x4 Dv = mfma16(X[a], WvB, cv);   // V[token][vcomp]
        const h4 qB = packC(Dq);   // B-frag: Q^T (contract comps)
        const h4 kA = packC(Dk);   // A-frag: K[token][comp]
        const h4 vA = packC(Dv);   // A-frag: V^T[vcomp][token]

        // ---- scores: S^T = K.Q^T per head (head = masked comp-half of A)
        const f32x4 S0 = mfma16(selh(scoreH0,  kA), qB, zz);
        const f32x4 S1 = mfma16(selh(!scoreH0, kA), qB, zz);

        // ---- in-lane softmax over the 4 regs (valid lanes: g2==c0>>2)
        const float e00 = __builtin_amdgcn_exp2f(S0[0] * C);
        const float e01 = __builtin_amdgcn_exp2f(S0[1] * C);
        const float e02 = __builtin_amdgcn_exp2f(S0[2] * C);
        const float e03 = __builtin_amdgcn_exp2f(S0[3] * C);
        const float e10 = __builtin_amdgcn_exp2f(S1[0] * C);
        const float e11 = __builtin_amdgcn_exp2f(S1[1] * C);
        const float e12 = __builtin_amdgcn_exp2f(S1[2] * C);
        const float e13 = __builtin_amdgcn_exp2f(S1[3] * C);
        const float r0 = __builtin_amdgcn_rcpf((e00 + e01) + (e02 + e03));
        const float r1 = __builtin_amdgcn_rcpf((e10 + e11) + (e12 + e13));
        // P^T B-frags; block-diagonal structure via zeroing invalid lanes
        const h4 PB0 = selh(valid, mkh4(bcu(pkrtz(e00 * r0, e01 * r0)),
                                        bcu(pkrtz(e02 * r0, e03 * r0))));
        const h4 PB1 = selh(valid, mkh4(bcu(pkrtz(e10 * r1, e11 * r1)),
                                        bcu(pkrtz(e12 * r1, e13 * r1))));

        // ---- PV: O^T = V^T.P^T, heads via masked v-comp rows, C-chained
        f32x4 Ot = mfma16(selh(pvH0,  vA), PB0, zz);
        Ot       = mfma16(selh(!pvH0, vA), PB1, Ot);
        const h4 hB = packC(Ot);   // B-frag: O^T (contract comps)

        // ---- h: H = W1^T.O^T (+b1); C-out col=token, rows=hid comps
        f32x4 ch0 = {b10.x, b10.y, b10.z, b10.w};
        f32x4 ch1 = {b11.x, b11.y, b11.z, b11.w};
        const f32x4 H0 = mfma16(EhA0, hB, ch0);
        const f32x4 H1 = mfma16(EhA1, hB, ch1);

        // ---- relu+pack: H C-out == A-frag of relu(H)^T (K = hid tile)
        const h4 AH0 = packCrelu(H0);
        const h4 AH1 = packCrelu(H1);

        // ---- fco per token: C-out col=oc(c0), rows = tokens 4g2..4g2+3 =
        //      ONE face -> pool = 3 in-lane adds (0.25 pre-folded in ws).
        const f32x4 O0 = mfma16(AH1, Ef10, mfma16(AH0, Ef00, zz));
        const f32x4 O1 = mfma16(AH1, Ef11, mfma16(AH0, Ef01, zz));
        const float o0 = ((O0[0] + O0[1]) + (O0[2] + O0[3])) + fb0s;
        const float o1 = ((O1[0] + O1[1]) + (O1[2] + O1[3])) + fb1s;

        // ---- coalesced store: quad transpose (6 DPP + 4 selects).
        //      Quad lanes share a face; lane t holds (o0,o1) for col c0=4q+t.
        //      After rot: lane t sees value of lane (t+j)&3 via rotj.
        //      t==0 stores float4(o0 of lanes 0..3) at col 4q;
        //      t==1 stores float4(o1 of lanes 0..3) = [b3,o1,b1,b2] at 16+4q.
        //      One instruction: 8 lanes/face cover the full 128B line;
        //      4 consecutive faces/wave-instr = 512B contiguous.
        const float a1 = dppf<DPP_ROT1>(o0);
        const float a2 = dppf<DPP_ROT2>(o0);
        const float a3 = dppf<DPP_ROT3>(o0);
        const float b1 = dppf<DPP_ROT1>(o1);
        const float b2 = dppf<DPP_ROT2>(o1);
        const float b3 = dppf<DPP_ROT3>(o1);
        const int face = fbase + 4 * a + g2;
        if ((c0 & 2) == 0 && face < F) {
            const bool t0 = (c0 & 1) == 0;
            const int q = c0 >> 2;
            const float4 st = make_float4(t0 ? o0 : b3,
                                          t0 ? a1 : o1,
                                          t0 ? a2 : b1,
                                          t0 ? a3 : b2);
            float* ob = out + (size_t)face * 32 + (t0 ? 4 * q : 16 + 4 * q);
            *reinterpret_cast<float4*>(ob) = st;
        }
    }
}

extern "C" void kernel_launch(void* const* d_in, const int* in_sizes, int n_in,
                              void* d_out, int out_size, void* d_ws, size_t ws_size,
                              hipStream_t stream) {
    const float* node  = (const float*)d_in[0];
    const int*   fids  = (const int*)  d_in[1];
    const float* w_in  = (const float*)d_in[2];
    const float* b_in  = (const float*)d_in[3];
    const float* w_out = (const float*)d_in[4];
    const float* b_out = (const float*)d_in[5];
    const float* fc_w  = (const float*)d_in[6];
    const float* fc_b  = (const float*)d_in[7];
    const float* fco_w = (const float*)d_in[8];
    const float* fco_b = (const float*)d_in[9];
    float* out = (float*)d_out;
    uint32_t* wsu = (uint32_t*)d_ws;
    const int F = in_sizes[1] / 4;

    hipLaunchKernelGGL(fold_w, dim3(2), dim3(640), 0, stream,
                       w_in, w_out, b_out, fc_w, fc_b, fco_w, wsu);
    const int threads = F * 4;
    const int blocks = (threads + 255) / 256;
    hipLaunchKernelGGL(face_net, dim3(blocks), dim3(256), 0, stream,
                       node, fids, b_in, wsu, fco_b, out, F);
}